// Round 17
// baseline (254.817 us; speedup 1.0000x reference)
//
#include <hip/hip_runtime.h>
#include <hip/hip_bf16.h>
#include <stdint.h>

static constexpr int NN = 50000;   // nodes
static constexpr int NE = 400000;  // edges
static constexpr int NB = (NN + 1023) / 1024;  // 49 scan blocks

// prelude block ranges
static constexpr int PB_CNT = (NE + 255) / 256;            // 1563
static constexpr int PB_CV  = (NN * 128 / 4 + 255) / 256;  // 6250
static constexpr int PB_W1  = (128 * 128) / 256;           // 64
static constexpr int PB_W2  = (128 * 256) / 256;           // 128
static constexpr int PB_W3  = (256 * 512) / 256;           // 512

typedef __attribute__((ext_vector_type(8))) short bf16x8;
typedef __attribute__((ext_vector_type(8))) unsigned short u16x8;
typedef __attribute__((ext_vector_type(4))) float f32x4;

__device__ inline ushort f2bf(float f) {
    __hip_bfloat16 b = __float2bfloat16(f);
    return *reinterpret_cast<ushort*>(&b);
}
__device__ inline float bfu2f(ushort u) {
    unsigned x = (unsigned)u << 16;
    return __builtin_bit_cast(float, x);
}

__device__ __forceinline__ void gload16(const void* g, void* l) {
    __builtin_amdgcn_global_load_lds(
        (const __attribute__((address_space(1))) void*)g,
        (__attribute__((address_space(3))) void*)l, 16, 0, 0);
}

// ------- fused prelude: count | castV | castW1 | castW2 | castW3 -------

__global__ void k_prelude(const int* __restrict__ ei, unsigned* __restrict__ cnt,
                          const float* __restrict__ v, ushort* __restrict__ vb,
                          const float* __restrict__ W1, ushort* __restrict__ Wt1,
                          const float* __restrict__ W2, ushort* __restrict__ Wt2,
                          const float* __restrict__ W3, ushort* __restrict__ Wt3) {
    int b = blockIdx.x;
    int tid = (int)threadIdx.x;
    if (b < PB_CNT) {
        int e = b * 256 + tid;
        if (e < NE) atomicAdd(&cnt[ei[NE + e]], 1u);
    } else if (b < PB_CNT + PB_CV) {
        int i = (b - PB_CNT) * 256 + tid;
        if (i < NN * 128 / 4) {
            float4 f = *reinterpret_cast<const float4*>(v + (size_t)i * 4);
            *reinterpret_cast<ushort4*>(vb + (size_t)i * 4) =
                make_ushort4(f2bf(f.x), f2bf(f.y), f2bf(f.z), f2bf(f.w));
        }
    } else if (b < PB_CNT + PB_CV + PB_W1) {
        int i = (b - PB_CNT - PB_CV) * 256 + tid;  // K=128, N=128
        int k = i >> 7, n = i & 127;
        Wt1[n * 128 + k] = f2bf(W1[i]);
    } else if (b < PB_CNT + PB_CV + PB_W1 + PB_W2) {
        int i = (b - PB_CNT - PB_CV - PB_W1) * 256 + tid;  // K=128, N=256
        int k = i >> 8, n = i & 255;
        Wt2[n * 128 + k] = f2bf(W2[i]);
    } else {
        int i = (b - PB_CNT - PB_CV - PB_W1 - PB_W2) * 256 + tid;  // K=256, N=512
        int k = i >> 9, n = i & 511;
        Wt3[n * 256 + k] = f2bf(W3[i]);
    }
}

// --- hierarchical exclusive scan (dinv fused into pass 1; passes 2+3 fused) ---

__global__ __launch_bounds__(1024) void k_scan1(const unsigned* __restrict__ cnt,
                                                unsigned* __restrict__ offs,
                                                unsigned* __restrict__ bsum,
                                                float* __restrict__ dinv) {
    __shared__ unsigned sh[1024];
    int i = blockIdx.x * 1024 + (int)threadIdx.x;
    unsigned v = (i < NN) ? cnt[i] : 0u;
    if (i < NN) dinv[i] = rsqrtf((float)(v + 1u));  // deg includes self-loop
    sh[threadIdx.x] = v;
    __syncthreads();
    #pragma unroll
    for (int off = 1; off < 1024; off <<= 1) {
        unsigned add = (threadIdx.x >= (unsigned)off) ? sh[threadIdx.x - off] : 0u;
        __syncthreads();
        sh[threadIdx.x] += add;
        __syncthreads();
    }
    if (i < NN) offs[i] = sh[threadIdx.x] - v;  // block-local exclusive
    if (threadIdx.x == 1023) bsum[blockIdx.x] = sh[1023];
}

// fused scan2+scan3: each block computes its own prefix of bsum inline and adds.
__global__ __launch_bounds__(1024) void k_scan23(unsigned* __restrict__ offs,
                                                 const unsigned* __restrict__ bsum) {
    int b = blockIdx.x;
    unsigned boff = 0;
    for (int j = 0; j < b; ++j) boff += bsum[j];  // <=48 L2 reads
    int i = b * 1024 + (int)threadIdx.x;
    if (i < NN) offs[i] += boff;
    if (b == 0 && threadIdx.x == 0) offs[NN] = NE;  // total is always NE
}

__global__ void k_fill(const int* __restrict__ ei, const unsigned* __restrict__ offs,
                       unsigned* __restrict__ cursor, const float* __restrict__ dinv,
                       unsigned* __restrict__ csr_src, float* __restrict__ csr_w) {
    int e = blockIdx.x * blockDim.x + threadIdx.x;
    if (e < NE) {
        int s = ei[e];
        int d = ei[NE + e];
        unsigned pos = offs[d] + atomicAdd(&cursor[d], 1u);
        csr_src[pos] = (unsigned)s;
        csr_w[pos] = dinv[s] * dinv[d];
    }
}

// ------- Aggregation: y = A_hat * x (bf16), 8 gathers in flight, index-prefetch -------

template <int VEC>  // F = 64*VEC
__global__ __launch_bounds__(256) void k_aggregate(
        const ushort* __restrict__ x, ushort* __restrict__ y,
        const unsigned* __restrict__ offs, const unsigned* __restrict__ csr_src,
        const float* __restrict__ csr_w, const float* __restrict__ dinv) {
    const int F = 64 * VEC;
    constexpr int LPR = (VEC == 2) ? 16 : 32;  // lanes per row (16B/lane)
    constexpr int NEP = 64 / LPR;              // parallel edge slots: 4 or 2
    constexpr int U = 8 / NEP;                 // per-slot unroll: 2 or 4
    int node = blockIdx.x * 4 + ((int)threadIdx.x >> 6);
    int lane = (int)threadIdx.x & 63;
    if (node >= NN) return;
    int h = lane / LPR;   // edge slot
    int sl = lane % LPR;  // 16B slice within row

    float di = dinv[node];
    float sw = (h == 0) ? di * di : 0.f;  // self term counted once
    float acc[8];
    {
        u16x8 u = *reinterpret_cast<const u16x8*>(x + (size_t)node * F + sl * 8);
        #pragma unroll
        for (int j = 0; j < 8; ++j) acc[j] = sw * bfu2f(u[j]);
    }

    unsigned beg = offs[node], end = offs[node + 1];
    unsigned e = beg + h;

    // software-pipelined main loop: next batch's indices issue before current gathers
    unsigned s[U]; float w[U];
    bool have = (e + NEP * (U - 1) < end);
    if (have) {
        #pragma unroll
        for (int k = 0; k < U; ++k) { s[k] = csr_src[e + NEP * k]; w[k] = csr_w[e + NEP * k]; }
    }
    while (have) {
        unsigned en = e + NEP * U;
        bool haveN = (en + NEP * (U - 1) < end);
        unsigned s2[U]; float w2[U];
        if (haveN) {
            #pragma unroll
            for (int k = 0; k < U; ++k) { s2[k] = csr_src[en + NEP * k]; w2[k] = csr_w[en + NEP * k]; }
        }
        u16x8 u[U];
        #pragma unroll
        for (int k = 0; k < U; ++k)
            u[k] = *reinterpret_cast<const u16x8*>(x + (size_t)s[k] * F + sl * 8);
        #pragma unroll
        for (int k = 0; k < U; ++k)
            #pragma unroll
            for (int j = 0; j < 8; ++j) acc[j] = fmaf(w[k], bfu2f(u[k][j]), acc[j]);
        e = en;
        #pragma unroll
        for (int k = 0; k < U; ++k) { s[k] = s2[k]; w[k] = w2[k]; }
        have = haveN;
    }
    for (; e < end; e += NEP) {
        unsigned s0 = csr_src[e];
        float w0 = csr_w[e];
        u16x8 u0 = *reinterpret_cast<const u16x8*>(x + (size_t)s0 * F + sl * 8);
        #pragma unroll
        for (int j = 0; j < 8; ++j) acc[j] = fmaf(w0, bfu2f(u0[j]), acc[j]);
    }

    #pragma unroll
    for (int j = 0; j < 8; ++j) {
        acc[j] += __shfl_xor(acc[j], 32);
        if constexpr (LPR == 16) acc[j] += __shfl_xor(acc[j], 16);
    }

    if (h == 0) {
        ushort hh[8];
        #pragma unroll
        for (int j = 0; j < 8; ++j) hh[j] = f2bf(acc[j]);
        *reinterpret_cast<u16x8*>(y + (size_t)node * F + sl * 8) =
            *reinterpret_cast<u16x8*>(hh);
    }
}

// ------- GEMM v9 + T5 setprio: 2-phase stage-before-compute, double-buffered B,
//         64x64 wave tiles, 3-stage A pipeline, LDS-transpose epilogue, NT fp32 out

template <int NT, int SC, bool OUTB>  // K = NT*32 ; SC = N/128
__global__ __launch_bounds__(256, 4) void k_gemm9(
        const ushort* __restrict__ Ah, const ushort* __restrict__ Wt,
        const float* __restrict__ bias, void* __restrict__ Cout, int M, int N) {
    constexpr int K = NT * 32;
    constexpr int CHT = 2;            // K-steps per chunk (16KB B)
    constexpr int NCH = NT / CHT;
    // 32KB: two 16KB B buffers; epilogue (17.4KB) overlays after final sync
    __shared__ __align__(16) float smem[8192];
    short* sB = (short*)smem;

    // bijective XCD swizzle
    int nwg = (int)gridDim.x;
    int bid = (int)blockIdx.x;
    int q = nwg >> 3, r = nwg & 7;
    int xcd = bid & 7, seq = bid >> 3;
    int swz = (xcd < r ? xcd * (q + 1) : r * (q + 1) + (xcd - r) * q) + seq;
    int bx = swz % SC, by = swz / SC;
    int col0 = bx * 128, row0 = by * 128;

    int tid = (int)threadIdx.x;
    int w = tid >> 6, lane = tid & 63;
    int wr = w >> 1, wc = w & 1;
    int r16 = lane & 15, kg = lane >> 4;

    size_t aoff[4];
    #pragma unroll
    for (int mi = 0; mi < 4; ++mi) {
        int row = row0 + wr * 64 + mi * 16 + r16;
        if (row >= M) row = M - 1;  // clamp reads; stores guarded
        aoff[mi] = (size_t)row * K + kg * 8;
    }

    auto stage = [&](int b, int kc) {
        short* dst = sB + b * 8192;  // 8192 shorts = 16KB
        #pragma unroll
        for (int i = 0; i < CHT * 2; ++i) {
            int c = i * 256 + tid;
            int tl = c >> 9, ckg = (c >> 7) & 3, n = c & 127;
            gload16(Wt + (size_t)(col0 + n) * K + (kc * CHT + tl) * 32 + ckg * 8,
                    dst + c * 8);
        }
    };

    f32x4 acc[4][4] = {};
    bf16x8 ah[3][4];  // 3-stage A pipeline (compile-time indexed: loops fully unrolled)

    #pragma unroll
    for (int mi = 0; mi < 4; ++mi)
        ah[0][mi] = *reinterpret_cast<const bf16x8*>(Ah + aoff[mi]);
    #pragma unroll
    for (int mi = 0; mi < 4; ++mi)
        ah[1][mi] = *reinterpret_cast<const bf16x8*>(Ah + aoff[mi] + 32);

    stage(0, 0);
    __syncthreads();

    #pragma unroll
    for (int kc = 0; kc < NCH; ++kc) {
        if (kc + 1 < NCH) stage((kc + 1) & 1, kc + 1);  // flies under this chunk's compute
        const short* sb = sB + (kc & 1) * 8192;
        #pragma unroll
        for (int t = 0; t < CHT; ++t) {
            const int tg = kc * CHT + t;  // compile-time under full unroll
            const int cur = tg % 3;
            if (tg + 2 < NT) {
                const int nxt = (tg + 2) % 3;
                #pragma unroll
                for (int mi = 0; mi < 4; ++mi)
                    ah[nxt][mi] = *reinterpret_cast<const bf16x8*>(Ah + aoff[mi] + (tg + 2) * 32);
            }
            bf16x8 bb[4];
            #pragma unroll
            for (int ni = 0; ni < 4; ++ni)
                bb[ni] = *reinterpret_cast<const bf16x8*>(
                    sb + ((t * 4 + kg) * 128 + wc * 64 + ni * 16 + r16) * 8);
            __builtin_amdgcn_s_setprio(1);  // favor MFMA-issuing wave on the CU scheduler
            #pragma unroll
            for (int ni = 0; ni < 4; ++ni)
                #pragma unroll
                for (int mi = 0; mi < 4; ++mi)
                    acc[mi][ni] = __builtin_amdgcn_mfma_f32_16x16x32_bf16(ah[cur][mi], bb[ni], acc[mi][ni], 0, 0, 0);
            __builtin_amdgcn_s_setprio(0);
        }
        __syncthreads();  // next-stage loads landed during compute; WAR-safe buffer swap
    }

    // ---- per-mi LDS-transpose epilogue (loop's final sync guards the overlay) ----
    float* ep = smem + w * (16 * 68);  // per-wave private 16x68 slice
    int crow0 = (lane >> 4) * 4;
    int ccol = lane & 15;
    int rb = row0 + wr * 64;
    int cb = col0 + wc * 64;
    int rl0 = lane >> 4;
    int cl = (lane & 15) * 4;
    float4 bv = *reinterpret_cast<const float4*>(&bias[cb + cl]);
    #pragma unroll
    for (int mi = 0; mi < 4; ++mi) {
        #pragma unroll
        for (int ni = 0; ni < 4; ++ni)
            #pragma unroll
            for (int j = 0; j < 4; ++j)
                ep[(crow0 + j) * 68 + ni * 16 + ccol] = acc[mi][ni][j];
        #pragma unroll
        for (int s = 0; s < 4; ++s) {
            int rl = s * 4 + rl0;
            int row = rb + mi * 16 + rl;
            if (row < M) {
                float4 vv = *reinterpret_cast<const float4*>(ep + rl * 68 + cl);
                float4 o;
                o.x = fmaxf(vv.x + bv.x, 0.f);
                o.y = fmaxf(vv.y + bv.y, 0.f);
                o.z = fmaxf(vv.z + bv.z, 0.f);
                o.w = fmaxf(vv.w + bv.w, 0.f);
                if constexpr (OUTB) {
                    *reinterpret_cast<ushort4*>((ushort*)Cout + (size_t)row * N + cb + cl) =
                        make_ushort4(f2bf(o.x), f2bf(o.y), f2bf(o.z), f2bf(o.w));
                } else {
                    f32x4 ov = {o.x, o.y, o.z, o.w};
                    __builtin_nontemporal_store(
                        ov, reinterpret_cast<f32x4*>((float*)Cout + (size_t)row * N + cb + cl));
                }
            }
        }
    }
}

// ---------------- launch ----------------

extern "C" void kernel_launch(void* const* d_in, const int* in_sizes, int n_in,
                              void* d_out, int out_size, void* d_ws, size_t ws_size,
                              hipStream_t stream) {
    const float* v  = (const float*)d_in[0];
    const int* ei   = (const int*)d_in[1];
    const float* W1 = (const float*)d_in[2];
    const float* b1 = (const float*)d_in[3];
    const float* W2 = (const float*)d_in[4];
    const float* b2 = (const float*)d_in[5];
    const float* W3 = (const float*)d_in[6];
    const float* b3 = (const float*)d_in[7];
    float* out = (float*)d_out;

    char* ws = (char*)d_ws;
    size_t off = 0;
    auto alloc = [&](size_t bytes) {
        void* p = ws + off;
        off = (off + bytes + 255) & ~(size_t)255;
        return p;
    };
    // cnt+cursor at front (memset together).
    unsigned* cnt    = (unsigned*)(ws + 0);
    unsigned* cursor = (unsigned*)(ws + (size_t)NN * 4);
    off = ((size_t)NN * 8 + 255) & ~(size_t)255;
    ushort* Wt1 = (ushort*)alloc(128 * 128 * 2);   // 32KB
    ushort* Wt2 = (ushort*)alloc(128 * 256 * 2);   // 64KB
    ushort* Wt3 = (ushort*)alloc(256 * 512 * 2);   // 256KB (dedicated; prelude-written)
    unsigned* offs    = (unsigned*)alloc((size_t)(NN + 1) * 4);
    float*    dinv    = (float*)alloc((size_t)NN * 4);
    unsigned* bsum    = (unsigned*)alloc((size_t)NB * 4);
    unsigned* csr_src = (unsigned*)alloc((size_t)NE * 4);
    float*    csr_w   = (float*)alloc((size_t)NE * 4);
    ushort* aggA = (ushort*)alloc((size_t)NN * 256 * 2);  // agg output (bf16)
    ushort* vb   = (ushort*)alloc((size_t)NN * 128 * 2);  // v cast bf16
    ushort* xb   = (ushort*)alloc((size_t)NN * 256 * 2);  // x1b/x2b activations bf16

    hipMemsetAsync(cnt, 0, (size_t)NN * 8, stream);  // cnt + cursor

    // fused prelude: count | castV | castW1 | castW2 | castW3
    k_prelude<<<PB_CNT + PB_CV + PB_W1 + PB_W2 + PB_W3, 256, 0, stream>>>(
        ei, cnt, v, vb, W1, Wt1, W2, Wt2, W3, Wt3);
    k_scan1<<<NB, 1024, 0, stream>>>(cnt, offs, bsum, dinv);
    k_scan23<<<NB, 1024, 0, stream>>>(offs, bsum);
    k_fill<<<(NE + 255) / 256, 256, 0, stream>>>(ei, offs, cursor, dinv, csr_src, csr_w);

    int aggGrid = (NN + 3) / 4;
    int gr = (NN + 127) / 128;  // 391 row-tiles

    // Layer 1: agg(vb) -> aggA ; GEMM K=128,N=128 -> x1b (bf16)
    k_aggregate<2><<<aggGrid, 256, 0, stream>>>(vb, aggA, offs, csr_src, csr_w, dinv);
    k_gemm9<4, 1, true><<<gr * 1, 256, 0, stream>>>(aggA, Wt1, b1, xb, NN, 128);

    // Layer 2: agg(x1b) -> aggA ; GEMM K=128,N=256 -> x2b (bf16)
    k_aggregate<2><<<aggGrid, 256, 0, stream>>>(xb, aggA, offs, csr_src, csr_w, dinv);
    k_gemm9<4, 2, true><<<gr * 2, 256, 0, stream>>>(aggA, Wt2, b2, xb, NN, 256);

    // Layer 3: agg(x2b) -> aggA ; GEMM K=256,N=512 -> out (fp32)
    k_aggregate<4><<<aggGrid, 256, 0, stream>>>(xb, aggA, offs, csr_src, csr_w, dinv);
    k_gemm9<8, 4, false><<<gr * 4, 256, 0, stream>>>(aggA, Wt3, b3, out, NN, 512);
}

// Round 18
// 221.822 us; speedup vs baseline: 1.1487x; 1.1487x over previous
//
#include <hip/hip_runtime.h>
#include <hip/hip_bf16.h>
#include <stdint.h>

static constexpr int NN = 50000;   // nodes
static constexpr int NE = 400000;  // edges
static constexpr int NB = (NN + 1023) / 1024;  // 49 scan blocks

// prelude block ranges
static constexpr int PB_CNT = (NE + 255) / 256;            // 1563
static constexpr int PB_CV  = (NN * 128 / 4 + 255) / 256;  // 6250
static constexpr int PB_W1  = (128 * 128) / 256;           // 64
static constexpr int PB_W2  = (128 * 256) / 256;           // 128
static constexpr int PB_W3  = (256 * 512) / 256;           // 512

typedef __attribute__((ext_vector_type(8))) short bf16x8;
typedef __attribute__((ext_vector_type(8))) unsigned short u16x8;
typedef __attribute__((ext_vector_type(4))) float f32x4;

__device__ inline ushort f2bf(float f) {
    __hip_bfloat16 b = __float2bfloat16(f);
    return *reinterpret_cast<ushort*>(&b);
}
__device__ inline float bfu2f(ushort u) {
    unsigned x = (unsigned)u << 16;
    return __builtin_bit_cast(float, x);
}

__device__ __forceinline__ void gload16(const void* g, void* l) {
    __builtin_amdgcn_global_load_lds(
        (const __attribute__((address_space(1))) void*)g,
        (__attribute__((address_space(3))) void*)l, 16, 0, 0);
}

// ------- fused prelude: count | castV | castW1 | castW2 | castW3 -------

__global__ void k_prelude(const int* __restrict__ ei, unsigned* __restrict__ cnt,
                          const float* __restrict__ v, ushort* __restrict__ vb,
                          const float* __restrict__ W1, ushort* __restrict__ Wt1,
                          const float* __restrict__ W2, ushort* __restrict__ Wt2,
                          const float* __restrict__ W3, ushort* __restrict__ Wt3) {
    int b = blockIdx.x;
    int tid = (int)threadIdx.x;
    if (b < PB_CNT) {
        int e = b * 256 + tid;
        if (e < NE) atomicAdd(&cnt[ei[NE + e]], 1u);
    } else if (b < PB_CNT + PB_CV) {
        int i = (b - PB_CNT) * 256 + tid;
        if (i < NN * 128 / 4) {
            float4 f = *reinterpret_cast<const float4*>(v + (size_t)i * 4);
            *reinterpret_cast<ushort4*>(vb + (size_t)i * 4) =
                make_ushort4(f2bf(f.x), f2bf(f.y), f2bf(f.z), f2bf(f.w));
        }
    } else if (b < PB_CNT + PB_CV + PB_W1) {
        int i = (b - PB_CNT - PB_CV) * 256 + tid;  // K=128, N=128
        int k = i >> 7, n = i & 127;
        Wt1[n * 128 + k] = f2bf(W1[i]);
    } else if (b < PB_CNT + PB_CV + PB_W1 + PB_W2) {
        int i = (b - PB_CNT - PB_CV - PB_W1) * 256 + tid;  // K=128, N=256
        int k = i >> 8, n = i & 255;
        Wt2[n * 128 + k] = f2bf(W2[i]);
    } else {
        int i = (b - PB_CNT - PB_CV - PB_W1 - PB_W2) * 256 + tid;  // K=256, N=512
        int k = i >> 9, n = i & 511;
        Wt3[n * 256 + k] = f2bf(W3[i]);
    }
}

// --- hierarchical exclusive scan (dinv fused into pass 1; passes 2+3 fused) ---

__global__ __launch_bounds__(1024) void k_scan1(const unsigned* __restrict__ cnt,
                                                unsigned* __restrict__ offs,
                                                unsigned* __restrict__ bsum,
                                                float* __restrict__ dinv) {
    __shared__ unsigned sh[1024];
    int i = blockIdx.x * 1024 + (int)threadIdx.x;
    unsigned v = (i < NN) ? cnt[i] : 0u;
    if (i < NN) dinv[i] = rsqrtf((float)(v + 1u));  // deg includes self-loop
    sh[threadIdx.x] = v;
    __syncthreads();
    #pragma unroll
    for (int off = 1; off < 1024; off <<= 1) {
        unsigned add = (threadIdx.x >= (unsigned)off) ? sh[threadIdx.x - off] : 0u;
        __syncthreads();
        sh[threadIdx.x] += add;
        __syncthreads();
    }
    if (i < NN) offs[i] = sh[threadIdx.x] - v;  // block-local exclusive
    if (threadIdx.x == 1023) bsum[blockIdx.x] = sh[1023];
}

// fused scan2+scan3: each block computes its own prefix of bsum inline and adds.
__global__ __launch_bounds__(1024) void k_scan23(unsigned* __restrict__ offs,
                                                 const unsigned* __restrict__ bsum) {
    int b = blockIdx.x;
    unsigned boff = 0;
    for (int j = 0; j < b; ++j) boff += bsum[j];  // <=48 L2 reads
    int i = b * 1024 + (int)threadIdx.x;
    if (i < NN) offs[i] += boff;
    if (b == 0 && threadIdx.x == 0) offs[NN] = NE;  // total is always NE
}

__global__ void k_fill(const int* __restrict__ ei, const unsigned* __restrict__ offs,
                       unsigned* __restrict__ cursor, const float* __restrict__ dinv,
                       unsigned* __restrict__ csr_src, float* __restrict__ csr_w) {
    int e = blockIdx.x * blockDim.x + threadIdx.x;
    if (e < NE) {
        int s = ei[e];
        int d = ei[NE + e];
        unsigned pos = offs[d] + atomicAdd(&cursor[d], 1u);
        csr_src[pos] = (unsigned)s;
        csr_w[pos] = dinv[s] * dinv[d];
    }
}

// ------- Aggregation: y = A_hat * x (bf16), 8 gathers in flight, index-prefetch -------

template <int VEC>  // F = 64*VEC
__global__ __launch_bounds__(256) void k_aggregate(
        const ushort* __restrict__ x, ushort* __restrict__ y,
        const unsigned* __restrict__ offs, const unsigned* __restrict__ csr_src,
        const float* __restrict__ csr_w, const float* __restrict__ dinv) {
    const int F = 64 * VEC;
    constexpr int LPR = (VEC == 2) ? 16 : 32;  // lanes per row (16B/lane)
    constexpr int NEP = 64 / LPR;              // parallel edge slots: 4 or 2
    constexpr int U = 8 / NEP;                 // per-slot unroll: 2 or 4
    int node = blockIdx.x * 4 + ((int)threadIdx.x >> 6);
    int lane = (int)threadIdx.x & 63;
    if (node >= NN) return;
    int h = lane / LPR;   // edge slot
    int sl = lane % LPR;  // 16B slice within row

    float di = dinv[node];
    float sw = (h == 0) ? di * di : 0.f;  // self term counted once
    float acc[8];
    {
        u16x8 u = *reinterpret_cast<const u16x8*>(x + (size_t)node * F + sl * 8);
        #pragma unroll
        for (int j = 0; j < 8; ++j) acc[j] = sw * bfu2f(u[j]);
    }

    unsigned beg = offs[node], end = offs[node + 1];
    unsigned e = beg + h;

    // software-pipelined main loop: next batch's indices issue before current gathers
    unsigned s[U]; float w[U];
    bool have = (e + NEP * (U - 1) < end);
    if (have) {
        #pragma unroll
        for (int k = 0; k < U; ++k) { s[k] = csr_src[e + NEP * k]; w[k] = csr_w[e + NEP * k]; }
    }
    while (have) {
        unsigned en = e + NEP * U;
        bool haveN = (en + NEP * (U - 1) < end);
        unsigned s2[U]; float w2[U];
        if (haveN) {
            #pragma unroll
            for (int k = 0; k < U; ++k) { s2[k] = csr_src[en + NEP * k]; w2[k] = csr_w[en + NEP * k]; }
        }
        u16x8 u[U];
        #pragma unroll
        for (int k = 0; k < U; ++k)
            u[k] = *reinterpret_cast<const u16x8*>(x + (size_t)s[k] * F + sl * 8);
        #pragma unroll
        for (int k = 0; k < U; ++k)
            #pragma unroll
            for (int j = 0; j < 8; ++j) acc[j] = fmaf(w[k], bfu2f(u[k][j]), acc[j]);
        e = en;
        #pragma unroll
        for (int k = 0; k < U; ++k) { s[k] = s2[k]; w[k] = w2[k]; }
        have = haveN;
    }
    for (; e < end; e += NEP) {
        unsigned s0 = csr_src[e];
        float w0 = csr_w[e];
        u16x8 u0 = *reinterpret_cast<const u16x8*>(x + (size_t)s0 * F + sl * 8);
        #pragma unroll
        for (int j = 0; j < 8; ++j) acc[j] = fmaf(w0, bfu2f(u0[j]), acc[j]);
    }

    #pragma unroll
    for (int j = 0; j < 8; ++j) {
        acc[j] += __shfl_xor(acc[j], 32);
        if constexpr (LPR == 16) acc[j] += __shfl_xor(acc[j], 16);
    }

    if (h == 0) {
        ushort hh[8];
        #pragma unroll
        for (int j = 0; j < 8; ++j) hh[j] = f2bf(acc[j]);
        *reinterpret_cast<u16x8*>(y + (size_t)node * F + sl * 8) =
            *reinterpret_cast<u16x8*>(hh);
    }
}

// ------- GEMM v9 (PROVEN R15/R16, setprio reverted): 2-phase stage-before-compute,
//         double-buffered B, 64x64 wave tiles, 3-stage A pipeline,
//         LDS-transpose epilogue, NT fp32 out -------

template <int NT, int SC, bool OUTB>  // K = NT*32 ; SC = N/128
__global__ __launch_bounds__(256, 4) void k_gemm9(
        const ushort* __restrict__ Ah, const ushort* __restrict__ Wt,
        const float* __restrict__ bias, void* __restrict__ Cout, int M, int N) {
    constexpr int K = NT * 32;
    constexpr int CHT = 2;            // K-steps per chunk (16KB B)
    constexpr int NCH = NT / CHT;
    // 32KB: two 16KB B buffers; epilogue (17.4KB) overlays after final sync
    __shared__ __align__(16) float smem[8192];
    short* sB = (short*)smem;

    // bijective XCD swizzle
    int nwg = (int)gridDim.x;
    int bid = (int)blockIdx.x;
    int q = nwg >> 3, r = nwg & 7;
    int xcd = bid & 7, seq = bid >> 3;
    int swz = (xcd < r ? xcd * (q + 1) : r * (q + 1) + (xcd - r) * q) + seq;
    int bx = swz % SC, by = swz / SC;
    int col0 = bx * 128, row0 = by * 128;

    int tid = (int)threadIdx.x;
    int w = tid >> 6, lane = tid & 63;
    int wr = w >> 1, wc = w & 1;
    int r16 = lane & 15, kg = lane >> 4;

    size_t aoff[4];
    #pragma unroll
    for (int mi = 0; mi < 4; ++mi) {
        int row = row0 + wr * 64 + mi * 16 + r16;
        if (row >= M) row = M - 1;  // clamp reads; stores guarded
        aoff[mi] = (size_t)row * K + kg * 8;
    }

    auto stage = [&](int b, int kc) {
        short* dst = sB + b * 8192;  // 8192 shorts = 16KB
        #pragma unroll
        for (int i = 0; i < CHT * 2; ++i) {
            int c = i * 256 + tid;
            int tl = c >> 9, ckg = (c >> 7) & 3, n = c & 127;
            gload16(Wt + (size_t)(col0 + n) * K + (kc * CHT + tl) * 32 + ckg * 8,
                    dst + c * 8);
        }
    };

    f32x4 acc[4][4] = {};
    bf16x8 ah[3][4];  // 3-stage A pipeline (compile-time indexed: loops fully unrolled)

    #pragma unroll
    for (int mi = 0; mi < 4; ++mi)
        ah[0][mi] = *reinterpret_cast<const bf16x8*>(Ah + aoff[mi]);
    #pragma unroll
    for (int mi = 0; mi < 4; ++mi)
        ah[1][mi] = *reinterpret_cast<const bf16x8*>(Ah + aoff[mi] + 32);

    stage(0, 0);
    __syncthreads();

    #pragma unroll
    for (int kc = 0; kc < NCH; ++kc) {
        if (kc + 1 < NCH) stage((kc + 1) & 1, kc + 1);  // flies under this chunk's compute
        const short* sb = sB + (kc & 1) * 8192;
        #pragma unroll
        for (int t = 0; t < CHT; ++t) {
            const int tg = kc * CHT + t;  // compile-time under full unroll
            const int cur = tg % 3;
            if (tg + 2 < NT) {
                const int nxt = (tg + 2) % 3;
                #pragma unroll
                for (int mi = 0; mi < 4; ++mi)
                    ah[nxt][mi] = *reinterpret_cast<const bf16x8*>(Ah + aoff[mi] + (tg + 2) * 32);
            }
            bf16x8 bb[4];
            #pragma unroll
            for (int ni = 0; ni < 4; ++ni)
                bb[ni] = *reinterpret_cast<const bf16x8*>(
                    sb + ((t * 4 + kg) * 128 + wc * 64 + ni * 16 + r16) * 8);
            #pragma unroll
            for (int ni = 0; ni < 4; ++ni)
                #pragma unroll
                for (int mi = 0; mi < 4; ++mi)
                    acc[mi][ni] = __builtin_amdgcn_mfma_f32_16x16x32_bf16(ah[cur][mi], bb[ni], acc[mi][ni], 0, 0, 0);
        }
        __syncthreads();  // next-stage loads landed during compute; WAR-safe buffer swap
    }

    // ---- per-mi LDS-transpose epilogue (loop's final sync guards the overlay) ----
    float* ep = smem + w * (16 * 68);  // per-wave private 16x68 slice
    int crow0 = (lane >> 4) * 4;
    int ccol = lane & 15;
    int rb = row0 + wr * 64;
    int cb = col0 + wc * 64;
    int rl0 = lane >> 4;
    int cl = (lane & 15) * 4;
    float4 bv = *reinterpret_cast<const float4*>(&bias[cb + cl]);
    #pragma unroll
    for (int mi = 0; mi < 4; ++mi) {
        #pragma unroll
        for (int ni = 0; ni < 4; ++ni)
            #pragma unroll
            for (int j = 0; j < 4; ++j)
                ep[(crow0 + j) * 68 + ni * 16 + ccol] = acc[mi][ni][j];
        #pragma unroll
        for (int s = 0; s < 4; ++s) {
            int rl = s * 4 + rl0;
            int row = rb + mi * 16 + rl;
            if (row < M) {
                float4 vv = *reinterpret_cast<const float4*>(ep + rl * 68 + cl);
                float4 o;
                o.x = fmaxf(vv.x + bv.x, 0.f);
                o.y = fmaxf(vv.y + bv.y, 0.f);
                o.z = fmaxf(vv.z + bv.z, 0.f);
                o.w = fmaxf(vv.w + bv.w, 0.f);
                if constexpr (OUTB) {
                    *reinterpret_cast<ushort4*>((ushort*)Cout + (size_t)row * N + cb + cl) =
                        make_ushort4(f2bf(o.x), f2bf(o.y), f2bf(o.z), f2bf(o.w));
                } else {
                    f32x4 ov = {o.x, o.y, o.z, o.w};
                    __builtin_nontemporal_store(
                        ov, reinterpret_cast<f32x4*>((float*)Cout + (size_t)row * N + cb + cl));
                }
            }
        }
    }
}

// ---------------- launch ----------------

extern "C" void kernel_launch(void* const* d_in, const int* in_sizes, int n_in,
                              void* d_out, int out_size, void* d_ws, size_t ws_size,
                              hipStream_t stream) {
    const float* v  = (const float*)d_in[0];
    const int* ei   = (const int*)d_in[1];
    const float* W1 = (const float*)d_in[2];
    const float* b1 = (const float*)d_in[3];
    const float* W2 = (const float*)d_in[4];
    const float* b2 = (const float*)d_in[5];
    const float* W3 = (const float*)d_in[6];
    const float* b3 = (const float*)d_in[7];
    float* out = (float*)d_out;

    char* ws = (char*)d_ws;
    size_t off = 0;
    auto alloc = [&](size_t bytes) {
        void* p = ws + off;
        off = (off + bytes + 255) & ~(size_t)255;
        return p;
    };
    // cnt+cursor at front (memset together).
    unsigned* cnt    = (unsigned*)(ws + 0);
    unsigned* cursor = (unsigned*)(ws + (size_t)NN * 4);
    off = ((size_t)NN * 8 + 255) & ~(size_t)255;
    ushort* Wt1 = (ushort*)alloc(128 * 128 * 2);   // 32KB
    ushort* Wt2 = (ushort*)alloc(128 * 256 * 2);   // 64KB
    ushort* Wt3 = (ushort*)alloc(256 * 512 * 2);   // 256KB (dedicated; prelude-written)
    unsigned* offs    = (unsigned*)alloc((size_t)(NN + 1) * 4);
    float*    dinv    = (float*)alloc((size_t)NN * 4);
    unsigned* bsum    = (unsigned*)alloc((size_t)NB * 4);
    unsigned* csr_src = (unsigned*)alloc((size_t)NE * 4);
    float*    csr_w   = (float*)alloc((size_t)NE * 4);
    ushort* aggA = (ushort*)alloc((size_t)NN * 256 * 2);  // agg output (bf16)
    ushort* vb   = (ushort*)alloc((size_t)NN * 128 * 2);  // v cast bf16
    ushort* xb   = (ushort*)alloc((size_t)NN * 256 * 2);  // x1b/x2b activations bf16

    hipMemsetAsync(cnt, 0, (size_t)NN * 8, stream);  // cnt + cursor

    // fused prelude: count | castV | castW1 | castW2 | castW3
    k_prelude<<<PB_CNT + PB_CV + PB_W1 + PB_W2 + PB_W3, 256, 0, stream>>>(
        ei, cnt, v, vb, W1, Wt1, W2, Wt2, W3, Wt3);
    k_scan1<<<NB, 1024, 0, stream>>>(cnt, offs, bsum, dinv);
    k_scan23<<<NB, 1024, 0, stream>>>(offs, bsum);
    k_fill<<<(NE + 255) / 256, 256, 0, stream>>>(ei, offs, cursor, dinv, csr_src, csr_w);

    int aggGrid = (NN + 3) / 4;
    int gr = (NN + 127) / 128;  // 391 row-tiles

    // Layer 1: agg(vb) -> aggA ; GEMM K=128,N=128 -> x1b (bf16)
    k_aggregate<2><<<aggGrid, 256, 0, stream>>>(vb, aggA, offs, csr_src, csr_w, dinv);
    k_gemm9<4, 1, true><<<gr * 1, 256, 0, stream>>>(aggA, Wt1, b1, xb, NN, 128);

    // Layer 2: agg(x1b) -> aggA ; GEMM K=128,N=256 -> x2b (bf16)
    k_aggregate<2><<<aggGrid, 256, 0, stream>>>(xb, aggA, offs, csr_src, csr_w, dinv);
    k_gemm9<4, 2, true><<<gr * 2, 256, 0, stream>>>(aggA, Wt2, b2, xb, NN, 256);

    // Layer 3: agg(x2b) -> aggA ; GEMM K=256,N=512 -> out (fp32)
    k_aggregate<4><<<aggGrid, 256, 0, stream>>>(xb, aggA, offs, csr_src, csr_w, dinv);
    k_gemm9<8, 4, false><<<gr * 4, 256, 0, stream>>>(aggA, Wt3, b3, out, NN, 512);
}